// Round 5
// baseline (187.591 us; speedup 1.0000x reference)
//
#include <hip/hip_runtime.h>

#define F 128
#define NO 256            // NUM_IRREPS = 2*F
#define CHUNK 32
#define THREADS 256
#define NBLK_HIST 64

typedef short bf16x8 __attribute__((ext_vector_type(8)));
typedef float f32x4 __attribute__((ext_vector_type(4)));
typedef unsigned short u16x8 __attribute__((ext_vector_type(8)));

// ws int layout
#define WS_COUNTS   0      // 64 ints
#define WS_OFFSETS  64
#define WS_BC       8192   // [64 hist-blocks][64 species]
#define WS_ORDER    16384  // N ints (ends ~66384)
#define WS_DESC     131072 // 3 ints per slot, up to ~13600 slots (ends < 1MB)
// ws byte offsets (weight panels)
#define WS_GKFRAG  (1u<<20)             // [S*16 ot][4 kk][64 lane][8] bf16 = 4MB
#define WS_LW0FRAG (5u<<20)             // [8 gt][4 kk][64][8] bf16 = 32KB
#define WS_LW1FRAG ((5u<<20) + 32768)

__device__ __forceinline__ unsigned short f2bf(float x) {
    union { float f; unsigned u; } v; v.f = x;
    unsigned r = (v.u + 0x7FFFu + ((v.u >> 16) & 1u)) >> 16;
    return (unsigned short)r;
}
__device__ __forceinline__ unsigned pack2(float a, float b) {
    return (unsigned)f2bf(a) | ((unsigned)f2bf(b) << 16);
}
__device__ __forceinline__ float bf2f(unsigned short h) {
    union { unsigned u; float f; } v; v.u = ((unsigned)h) << 16; return v.f;
}

// ---- init: zero counts + mark all descriptor slots empty ----
__global__ void k_init(int* __restrict__ wsI, int maxslots) {
    int gid = blockIdx.x * 256 + threadIdx.x;
    if (gid < 64) wsI[WS_COUNTS + gid] = 0;
    if (gid < maxslots) {
        wsI[WS_DESC + 3 * gid]     = -1;
        wsI[WS_DESC + 3 * gid + 1] = 0;
        wsI[WS_DESC + 3 * gid + 2] = 0;
    }
}

// ---- prep: weight fragments ----
__global__ __launch_bounds__(256) void k_prep(const float* __restrict__ gk,
                                              const float* __restrict__ lw0,
                                              const float* __restrict__ lw1,
                                              unsigned* __restrict__ gkfrag,
                                              unsigned* __restrict__ lw0f,
                                              unsigned* __restrict__ lw1f,
                                              int S) {
    int t = threadIdx.x, lane = t & 63, grp = t >> 6;
    int lr = lane & 15, lg = lane >> 4;
    int b = blockIdx.x;
    if (b < S) {
        const float* src = gk + (size_t)b * F * NO;
        #pragma unroll
        for (int it = 0; it < 4; ++it) {
            int ot = grp * 4 + it;
            #pragma unroll
            for (int kk = 0; kk < 4; ++kk) {
                float v[8];
                #pragma unroll
                for (int e = 0; e < 8; ++e)
                    v[e] = src[(kk * 32 + lg * 8 + e) * NO + ot * 16 + lr];
                uint4 pk;
                pk.x = pack2(v[0], v[1]); pk.y = pack2(v[2], v[3]);
                pk.z = pack2(v[4], v[5]); pk.w = pack2(v[6], v[7]);
                *(uint4*)((char*)gkfrag + ((size_t)((b * 16 + ot) * 4 + kk) * 1024) + lane * 16) = pk;
            }
        }
    } else if (b == S || b == S + 1) {
        const float* src = (b == S) ? lw0 : lw1;
        unsigned* dst = (b == S) ? lw0f : lw1f;
        const float inv = 0.08838834764831845f; // 1/sqrt(128)
        #pragma unroll
        for (int it = 0; it < 2; ++it) {
            int gt = grp * 2 + it;
            #pragma unroll
            for (int kk = 0; kk < 4; ++kk) {
                float v[8];
                #pragma unroll
                for (int e = 0; e < 8; ++e)
                    v[e] = src[(kk * 32 + lg * 8 + e) * F + gt * 16 + lr] * inv;
                uint4 pk;
                pk.x = pack2(v[0], v[1]); pk.y = pack2(v[2], v[3]);
                pk.z = pack2(v[4], v[5]); pk.w = pack2(v[6], v[7]);
                *(uint4*)((char*)dst + ((gt * 4 + kk) * 1024) + lane * 16) = pk;
            }
        }
    }
}

// ---- hist: per-block counts + global counts ----
__global__ void k_hist(const int* __restrict__ spec, int N, int* __restrict__ wsI) {
    __shared__ int h[64];
    int t = threadIdx.x, b = blockIdx.x;
    if (t < 64) h[t] = 0;
    __syncthreads();
    int per = (N + NBLK_HIST - 1) / NBLK_HIST;
    int lo = b * per, hi = min(N, lo + per);
    for (int i = lo + t; i < hi; i += 256) atomicAdd(&h[spec[i]], 1);
    __syncthreads();
    if (t < 64) {
        wsI[WS_BC + b * 64 + t] = h[t];
        if (h[t]) atomicAdd(&wsI[WS_COUNTS + t], h[t]);
    }
}

// ---- plan: prefix sums, per-block bases, XCD-bucketed chunk descriptors ----
__global__ void k_plan(int* __restrict__ wsI, int S) {
    int t = threadIdx.x;
    int cnt = (t < S) ? wsI[WS_COUNTS + t] : 0;
    int nch = (cnt + CHUNK - 1) / CHUNK;
    int x = cnt;
    #pragma unroll
    for (int d = 1; d < 64; d <<= 1) {
        int v = __shfl_up(x, d);
        if (t >= d) x += v;
    }
    int off = x - cnt;
    // stride-8 scan: rank of this species' chunks within its XCD bucket
    int y = nch;
    #pragma unroll
    for (int d = 8; d < 64; d <<= 1) {
        int v = __shfl_up(y, d);
        if (t >= d) y += v;
    }
    int rank0 = y - nch;
    if (t < S) {
        wsI[WS_OFFSETS + t] = off;
        int run = off;
        for (int b2 = 0; b2 < NBLK_HIST; ++b2) {
            int tmp = wsI[WS_BC + b2 * 64 + t];
            wsI[WS_BC + b2 * 64 + t] = run;
            run += tmp;
        }
        for (int c = 0; c < nch; ++c) {
            int slot = 8 * (rank0 + c) + (t & 7);   // same species -> same XCD (bid%8)
            int* dsc = &wsI[WS_DESC + 3 * slot];
            dsc[0] = t;
            dsc[1] = off + c * CHUNK;
            dsc[2] = min(CHUNK, cnt - c * CHUNK);
        }
    }
}

// ---- scatter: blockwise deterministic-range scatter ----
__global__ void k_scatter(const int* __restrict__ spec, int N, int* __restrict__ wsI) {
    __shared__ int cur[64];
    int t = threadIdx.x, b = blockIdx.x;
    if (t < 64) cur[t] = wsI[WS_BC + b * 64 + t];
    __syncthreads();
    int per = (N + NBLK_HIST - 1) / NBLK_HIST;
    int lo = b * per, hi = min(N, lo + per);
    for (int i = lo + t; i < hi; i += 256) {
        int pos = atomicAdd(&cur[spec[i]], 1);
        wsI[WS_ORDER + pos] = i;
    }
}

// ---- main: one 32-node same-species chunk per block ----
__global__ __launch_bounds__(THREADS, 4) void k_main(
    const float* __restrict__ nf,
    const float* __restrict__ w0,
    const float* __restrict__ w1,
    const unsigned short* __restrict__ gkfrag,
    const float* __restrict__ gb,
    const unsigned short* __restrict__ lw0f,
    const unsigned short* __restrict__ lw1f,
    const int* __restrict__ wsI,
    float* __restrict__ out)
{
    int b = blockIdx.x;
    int s = wsI[WS_DESC + 3 * b];
    if (s < 0) return;
    int start = wsI[WS_DESC + 3 * b + 1];
    int cnt   = wsI[WS_DESC + 3 * b + 2];

    __shared__ __align__(16) unsigned short s_ab[CHUNK * 136];   // out0/out0g bf16; later y0 f32 stage [16][132]
    __shared__ __align__(16) float s_u[6528];                    // union: gate bf16 [32][280] / out1g bf16 [3][32][136] / y1 f32 stage [16][388]
    __shared__ int s_nid[CHUNK];

    int t = threadIdx.x;
    int lane = t & 63, w = t >> 6, lr = lane & 15, lg = lane >> 4;
    int n = t >> 3, j = t & 7, f0 = j * 16;

    int nid = (n < cnt) ? wsI[WS_ORDER + start + n] : -1;
    if (j == 0) s_nid[n] = nid;

    const float* p = nf + (size_t)(nid >= 0 ? nid : 0) * 512;

    // ---- phase 1: polynomial paths (registers) ----
    float x0[16], dot[16], o0[16], c1[16];
    {
        #pragma unroll
        for (int v = 0; v < 4; ++v)
            *(float4*)&x0[4 * v] = *(const float4*)&p[f0 + 4 * v];
        #pragma unroll
        for (int h = 0; h < 2; ++h) {
            float q[24];
            #pragma unroll
            for (int v = 0; v < 6; ++v)
                *(float4*)&q[4 * v] = *(const float4*)&p[128 + f0 * 3 + 24 * h + 4 * v];
            #pragma unroll
            for (int i = 0; i < 8; ++i)
                dot[8 * h + i] = q[3 * i] * q[3 * i] + q[3 * i + 1] * q[3 * i + 1] + q[3 * i + 2] * q[3 * i + 2];
        }
        if (nid < 0) {
            #pragma unroll
            for (int i = 0; i < 16; ++i) { x0[i] = 0.f; dot[i] = 0.f; }
        }
        const float* W0 = w0 + s * 5 * F + f0;
        const float* W1 = w1 + s * 4 * F + f0;
        float wr[16];
        #define LOADW(base) { \
            *(float4*)&wr[0]  = *(const float4*)&(base)[0]; \
            *(float4*)&wr[4]  = *(const float4*)&(base)[4]; \
            *(float4*)&wr[8]  = *(const float4*)&(base)[8]; \
            *(float4*)&wr[12] = *(const float4*)&(base)[12]; }
        LOADW(W0);
        #pragma unroll
        for (int i = 0; i < 16; ++i) o0[i] = x0[i] * wr[i];
        LOADW((W0 + F));
        #pragma unroll
        for (int i = 0; i < 16; ++i) o0[i] += x0[i] * x0[i] * wr[i];
        LOADW((W0 + 2 * F));
        #pragma unroll
        for (int i = 0; i < 16; ++i) o0[i] += dot[i] * wr[i];
        LOADW((W0 + 3 * F));
        #pragma unroll
        for (int i = 0; i < 16; ++i) o0[i] += x0[i] * x0[i] * x0[i] * wr[i];
        LOADW((W0 + 4 * F));
        #pragma unroll
        for (int i = 0; i < 16; ++i) o0[i] += x0[i] * dot[i] * wr[i];
        LOADW(W1);
        #pragma unroll
        for (int i = 0; i < 16; ++i) c1[i] = wr[i];
        LOADW((W1 + F));
        #pragma unroll
        for (int i = 0; i < 16; ++i) c1[i] += x0[i] * wr[i];
        LOADW((W1 + 2 * F));
        #pragma unroll
        for (int i = 0; i < 16; ++i) c1[i] += x0[i] * x0[i] * wr[i];
        LOADW((W1 + 3 * F));
        #pragma unroll
        for (int i = 0; i < 16; ++i) c1[i] += dot[i] * wr[i];
        #undef LOADW
    }
    {
        uint4 pk0, pk1;
        pk0.x = pack2(o0[0], o0[1]);  pk0.y = pack2(o0[2], o0[3]);
        pk0.z = pack2(o0[4], o0[5]);  pk0.w = pack2(o0[6], o0[7]);
        pk1.x = pack2(o0[8], o0[9]);  pk1.y = pack2(o0[10], o0[11]);
        pk1.z = pack2(o0[12], o0[13]); pk1.w = pack2(o0[14], o0[15]);
        *(uint4*)&s_ab[n * 136 + f0] = pk0;
        *(uint4*)&s_ab[n * 136 + f0 + 8] = pk1;
    }

    // prefetch gate-kernel B-fragments (per wave: ot = 4w..4w+3)
    bf16x8 Bg[4][4];
    {
        const unsigned short* gkb = gkfrag + (size_t)((s * 16 + 4 * w) * 4) * 512 + lane * 8;
        #pragma unroll
        for (int oi = 0; oi < 4; ++oi)
            #pragma unroll
            for (int kk = 0; kk < 4; ++kk)
                Bg[oi][kk] = *(const bf16x8*)(gkb + (oi * 4 + kk) * 512);
    }
    __syncthreads();   // B1: s_ab ready

    // ---- phase 2: gate = out0 @ gk + gb, stored bf16 [node][280] ----
    unsigned short* s_g = (unsigned short*)s_u;
    {
        int obase = w * 64;
        float gbv[4];
        #pragma unroll
        for (int oi = 0; oi < 4; ++oi) gbv[oi] = gb[s * NO + obase + oi * 16 + lr];
        #pragma unroll
        for (int nt = 0; nt < 2; ++nt) {
            bf16x8 A[4];
            #pragma unroll
            for (int kk = 0; kk < 4; ++kk)
                A[kk] = *(const bf16x8*)&s_ab[(nt * 16 + lr) * 136 + kk * 32 + lg * 8];
            #pragma unroll
            for (int oi = 0; oi < 4; ++oi) {
                f32x4 acc; acc[0] = gbv[oi]; acc[1] = gbv[oi]; acc[2] = gbv[oi]; acc[3] = gbv[oi];
                #pragma unroll
                for (int kk = 0; kk < 4; ++kk)
                    acc = __builtin_amdgcn_mfma_f32_16x16x32_bf16(A[kk], Bg[oi][kk], acc, 0, 0, 0);
                #pragma unroll
                for (int r = 0; r < 4; ++r)
                    s_g[(nt * 16 + lg * 4 + r) * 280 + obase + oi * 16 + lr] = f2bf(acc[r]);
            }
        }
    }
    __syncthreads();   // B2: gate ready

    // ---- phase 3a: read gate (bf16) to regs ----
    float g0[16], g1[16];
    {
        u16x8 v0a = *(const u16x8*)&s_g[n * 280 + f0];
        u16x8 v0b = *(const u16x8*)&s_g[n * 280 + f0 + 8];
        u16x8 v1a = *(const u16x8*)&s_g[n * 280 + 128 + f0];
        u16x8 v1b = *(const u16x8*)&s_g[n * 280 + 128 + f0 + 8];
        #pragma unroll
        for (int i = 0; i < 8; ++i) {
            g0[i] = bf2f(v0a[i]); g0[8 + i] = bf2f(v0b[i]);
            g1[i] = bf2f(v1a[i]); g1[8 + i] = bf2f(v1b[i]);
        }
    }
    __syncthreads();   // B3: gate region reusable

    // ---- phase 3b: apply gate; emit out0g -> s_ab, out1g -> s_o1 (union) ----
    unsigned short* s_o1 = (unsigned short*)s_u;
    {
        #pragma unroll
        for (int i = 0; i < 16; ++i) { o0[i] *= g0[i]; c1[i] *= g1[i]; }
        uint4 pk0, pk1;
        pk0.x = pack2(o0[0], o0[1]);  pk0.y = pack2(o0[2], o0[3]);
        pk0.z = pack2(o0[4], o0[5]);  pk0.w = pack2(o0[6], o0[7]);
        pk1.x = pack2(o0[8], o0[9]);  pk1.y = pack2(o0[10], o0[11]);
        pk1.z = pack2(o0[12], o0[13]); pk1.w = pack2(o0[14], o0[15]);
        *(uint4*)&s_ab[n * 136 + f0] = pk0;
        *(uint4*)&s_ab[n * 136 + f0 + 8] = pk1;
    }
    // prefetch lin-weight B-fragments (per wave: gt = 2w, 2w+1)
    bf16x8 L0[2][4], L1[2][4];
    {
        const unsigned short* l0b = lw0f + (size_t)(w * 2 * 4) * 512 + lane * 8;
        const unsigned short* l1b = lw1f + (size_t)(w * 2 * 4) * 512 + lane * 8;
        #pragma unroll
        for (int gi = 0; gi < 2; ++gi)
            #pragma unroll
            for (int kk = 0; kk < 4; ++kk) {
                L0[gi][kk] = *(const bf16x8*)(l0b + (gi * 4 + kk) * 512);
                L1[gi][kk] = *(const bf16x8*)(l1b + (gi * 4 + kk) * 512);
            }
    }
    {
        #pragma unroll
        for (int h = 0; h < 2; ++h) {
            float q[24];
            #pragma unroll
            for (int v = 0; v < 6; ++v)
                *(float4*)&q[4 * v] = *(const float4*)&p[128 + f0 * 3 + 24 * h + 4 * v];
            if (nid < 0) {
                #pragma unroll
                for (int i = 0; i < 24; ++i) q[i] = 0.f;
            }
            #pragma unroll
            for (int d = 0; d < 3; ++d) {
                uint4 pk;
                pk.x = pack2(c1[8 * h + 0] * q[0 + d],  c1[8 * h + 1] * q[3 + d]);
                pk.y = pack2(c1[8 * h + 2] * q[6 + d],  c1[8 * h + 3] * q[9 + d]);
                pk.z = pack2(c1[8 * h + 4] * q[12 + d], c1[8 * h + 5] * q[15 + d]);
                pk.w = pack2(c1[8 * h + 6] * q[18 + d], c1[8 * h + 7] * q[21 + d]);
                *(uint4*)&s_o1[(d * CHUNK + n) * 136 + f0 + 8 * h] = pk;
            }
        }
    }
    __syncthreads();   // B4: out0g/out1g ready

    // ---- phase 4a: all MFMAs into registers ----
    f32x4 y0a[2][2];        // [nt][gi]
    f32x4 y1a[2][3][2];     // [nt][d][gi]
    #pragma unroll
    for (int nt = 0; nt < 2; ++nt) {
        bf16x8 A[4];
        #pragma unroll
        for (int kk = 0; kk < 4; ++kk)
            A[kk] = *(const bf16x8*)&s_ab[(nt * 16 + lr) * 136 + kk * 32 + lg * 8];
        #pragma unroll
        for (int gi = 0; gi < 2; ++gi) {
            f32x4 acc = {0.f, 0.f, 0.f, 0.f};
            #pragma unroll
            for (int kk = 0; kk < 4; ++kk)
                acc = __builtin_amdgcn_mfma_f32_16x16x32_bf16(A[kk], L0[gi][kk], acc, 0, 0, 0);
            y0a[nt][gi] = acc;
        }
        #pragma unroll
        for (int d = 0; d < 3; ++d) {
            bf16x8 Ad[4];
            #pragma unroll
            for (int kk = 0; kk < 4; ++kk)
                Ad[kk] = *(const bf16x8*)&s_o1[(d * CHUNK + nt * 16 + lr) * 136 + kk * 32 + lg * 8];
            #pragma unroll
            for (int gi = 0; gi < 2; ++gi) {
                f32x4 acc = {0.f, 0.f, 0.f, 0.f};
                #pragma unroll
                for (int kk = 0; kk < 4; ++kk)
                    acc = __builtin_amdgcn_mfma_f32_16x16x32_bf16(Ad[kk], L1[gi][kk], acc, 0, 0, 0);
                y1a[nt][d][gi] = acc;
            }
        }
    }
    __syncthreads();   // B5: all LDS reads of s_ab/s_u done

    // ---- phase 4b: stage + full-wave contiguous flush, one 16-node half at a time ----
    float* sy0 = (float*)s_ab;   // f32 [16][132]
    float* sy1 = s_u;            // f32 [16][388]
    #pragma unroll
    for (int nt = 0; nt < 2; ++nt) {
        #pragma unroll
        for (int gi = 0; gi < 2; ++gi)
            #pragma unroll
            for (int r = 0; r < 4; ++r)
                sy0[(lg * 4 + r) * 132 + w * 32 + gi * 16 + lr] = y0a[nt][gi][r];
        #pragma unroll
        for (int d = 0; d < 3; ++d)
            #pragma unroll
            for (int gi = 0; gi < 2; ++gi)
                #pragma unroll
                for (int r = 0; r < 4; ++r)
                    sy1[(lg * 4 + r) * 388 + (w * 32 + gi * 16 + lr) * 3 + d] = y1a[nt][d][gi][r];
        __syncthreads();   // staging visible
        #pragma unroll
        for (int ni = 0; ni < 4; ++ni) {
            int node_l = w * 4 + ni;
            int nid2 = s_nid[nt * 16 + node_l];
            if (nid2 >= 0) {
                float* orow = out + (size_t)nid2 * 512;
                {
                    int col = lane * 4;
                    const float* src = (lane < 32) ? &sy0[node_l * 132 + col]
                                                   : &sy1[node_l * 388 + col - 128];
                    *(float4*)&orow[col] = *(const float4*)src;
                }
                {
                    int col = 256 + lane * 4;
                    *(float4*)&orow[col] = *(const float4*)&sy1[node_l * 388 + col - 128];
                }
            }
        }
        if (nt == 0) __syncthreads();   // staging reusable
    }
}

extern "C" void kernel_launch(void* const* d_in, const int* in_sizes, int n_in,
                              void* d_out, int out_size, void* d_ws, size_t ws_size,
                              hipStream_t stream) {
    const float* nf  = (const float*)d_in[0];
    const int*  spec = (const int*)d_in[1];
    const float* w0  = (const float*)d_in[2];
    const float* w1  = (const float*)d_in[3];
    const float* gk  = (const float*)d_in[4];
    const float* gb  = (const float*)d_in[5];
    const float* lw0 = (const float*)d_in[6];
    const float* lw1 = (const float*)d_in[7];
    float* out = (float*)d_out;

    int N = in_sizes[0] / (4 * F);
    int S = in_sizes[5] / NO;
    int* wsI = (int*)d_ws;
    unsigned* gkfrag = (unsigned*)((char*)d_ws + WS_GKFRAG);
    unsigned* lw0f   = (unsigned*)((char*)d_ws + WS_LW0FRAG);
    unsigned* lw1f   = (unsigned*)((char*)d_ws + WS_LW1FRAG);

    int maxslots = 8 * (N / CHUNK + S);   // worst-case: every chunk in one bucket

    k_init<<<(maxslots + 255) / 256, 256, 0, stream>>>(wsI, maxslots);
    k_hist<<<NBLK_HIST, 256, 0, stream>>>(spec, N, wsI);
    k_plan<<<1, 64, 0, stream>>>(wsI, S);
    k_scatter<<<NBLK_HIST, 256, 0, stream>>>(spec, N, wsI);
    k_prep<<<S + 2, 256, 0, stream>>>(gk, lw0, lw1, gkfrag, lw0f, lw1f, S);

    k_main<<<maxslots, THREADS, 0, stream>>>(nf, w0, w1,
                                             (const unsigned short*)gkfrag, gb,
                                             (const unsigned short*)lw0f,
                                             (const unsigned short*)lw1f,
                                             wsI, out);
}

// Round 6
// 92.797 us; speedup vs baseline: 2.0215x; 2.0215x over previous
//
#include <hip/hip_runtime.h>

#define F 128
#define NO 256            // NUM_IRREPS = 2*F
#define CHUNK 32
#define THREADS 256
#define NBLK_HIST 64

typedef short bf16x8 __attribute__((ext_vector_type(8)));
typedef float f32x4 __attribute__((ext_vector_type(4)));
typedef unsigned short u16x8 __attribute__((ext_vector_type(8)));

// ws int layout
#define WS_COUNTS   0      // 64 ints
#define WS_OFFSETS  64
#define WS_NCHUNKS  192
#define WS_DESC     256    // 3 ints per chunk
#define WS_BC       8192   // [64 hist-blocks][64 species]
#define WS_ORDER    16384  // N ints
// ws byte offsets (weight panels)
#define WS_GKFRAG  (1u<<20)             // [S*16 ot][4 kk][64 lane][8] bf16 = 4MB
#define WS_LW0FRAG (5u<<20)             // [8 gt][4 kk][64][8] bf16 = 32KB
#define WS_LW1FRAG ((5u<<20) + 32768)

__device__ __forceinline__ unsigned short f2bf(float x) {
    union { float f; unsigned u; } v; v.f = x;
    unsigned r = (v.u + 0x7FFFu + ((v.u >> 16) & 1u)) >> 16;
    return (unsigned short)r;
}
__device__ __forceinline__ unsigned pack2(float a, float b) {
    return (unsigned)f2bf(a) | ((unsigned)f2bf(b) << 16);
}
__device__ __forceinline__ float bf2f(unsigned short h) {
    union { unsigned u; float f; } v; v.u = ((unsigned)h) << 16; return v.f;
}

// ---- prep: weight fragments (and zero counts) ----
__global__ __launch_bounds__(256) void k_prep(const float* __restrict__ gk,
                                              const float* __restrict__ lw0,
                                              const float* __restrict__ lw1,
                                              int* __restrict__ wsI,
                                              unsigned* __restrict__ gkfrag,
                                              unsigned* __restrict__ lw0f,
                                              unsigned* __restrict__ lw1f,
                                              int S) {
    int t = threadIdx.x, lane = t & 63, grp = t >> 6;
    int lr = lane & 15, lg = lane >> 4;
    int b = blockIdx.x;
    if (b < S) {
        const float* src = gk + (size_t)b * F * NO;
        #pragma unroll
        for (int it = 0; it < 4; ++it) {
            int ot = grp * 4 + it;
            #pragma unroll
            for (int kk = 0; kk < 4; ++kk) {
                float v[8];
                #pragma unroll
                for (int e = 0; e < 8; ++e)
                    v[e] = src[(kk * 32 + lg * 8 + e) * NO + ot * 16 + lr];
                uint4 pk;
                pk.x = pack2(v[0], v[1]); pk.y = pack2(v[2], v[3]);
                pk.z = pack2(v[4], v[5]); pk.w = pack2(v[6], v[7]);
                *(uint4*)((char*)gkfrag + ((size_t)((b * 16 + ot) * 4 + kk) * 1024) + lane * 16) = pk;
            }
        }
    } else if (b == S || b == S + 1) {
        const float* src = (b == S) ? lw0 : lw1;
        unsigned* dst = (b == S) ? lw0f : lw1f;
        const float inv = 0.08838834764831845f; // 1/sqrt(128)
        #pragma unroll
        for (int it = 0; it < 2; ++it) {
            int gt = grp * 2 + it;
            #pragma unroll
            for (int kk = 0; kk < 4; ++kk) {
                float v[8];
                #pragma unroll
                for (int e = 0; e < 8; ++e)
                    v[e] = src[(kk * 32 + lg * 8 + e) * F + gt * 16 + lr] * inv;
                uint4 pk;
                pk.x = pack2(v[0], v[1]); pk.y = pack2(v[2], v[3]);
                pk.z = pack2(v[4], v[5]); pk.w = pack2(v[6], v[7]);
                *(uint4*)((char*)dst + ((gt * 4 + kk) * 1024) + lane * 16) = pk;
            }
        }
        if (b == S && t < 64) wsI[WS_COUNTS + t] = 0;
    }
}

// ---- hist: per-block counts + global counts ----
__global__ void k_hist(const int* __restrict__ spec, int N, int* __restrict__ wsI) {
    __shared__ int h[64];
    int t = threadIdx.x, b = blockIdx.x;
    if (t < 64) h[t] = 0;
    __syncthreads();
    int per = (N + NBLK_HIST - 1) / NBLK_HIST;
    int lo = b * per, hi = min(N, lo + per);
    for (int i = lo + t; i < hi; i += 256) atomicAdd(&h[spec[i]], 1);
    __syncthreads();
    if (t < 64) {
        wsI[WS_BC + b * 64 + t] = h[t];
        if (h[t]) atomicAdd(&wsI[WS_COUNTS + t], h[t]);
    }
}

// ---- plan: prefix sums, per-block bases, chunk descriptors ----
__global__ void k_plan(int* __restrict__ wsI, int S) {
    int t = threadIdx.x;
    int cnt = (t < S) ? wsI[WS_COUNTS + t] : 0;
    int nch = (cnt + CHUNK - 1) / CHUNK;
    int x = cnt, y = nch;
    #pragma unroll
    for (int d = 1; d < 64; d <<= 1) {
        int vx = __shfl_up(x, d);
        int vy = __shfl_up(y, d);
        if (t >= d) { x += vx; y += vy; }
    }
    int off = x - cnt, cbase = y - nch;
    if (t < S) {
        wsI[WS_OFFSETS + t] = off;
        int run = off;
        for (int b2 = 0; b2 < NBLK_HIST; ++b2) {
            int tmp = wsI[WS_BC + b2 * 64 + t];
            wsI[WS_BC + b2 * 64 + t] = run;
            run += tmp;
        }
        for (int c = 0; c < nch; ++c) {
            int* dsc = &wsI[WS_DESC + 3 * (cbase + c)];
            dsc[0] = t;
            dsc[1] = off + c * CHUNK;
            dsc[2] = min(CHUNK, cnt - c * CHUNK);
        }
    }
    if (t == 63) wsI[WS_NCHUNKS] = y;
}

// ---- scatter: blockwise deterministic-range scatter ----
__global__ void k_scatter(const int* __restrict__ spec, int N, int* __restrict__ wsI) {
    __shared__ int cur[64];
    int t = threadIdx.x, b = blockIdx.x;
    if (t < 64) cur[t] = wsI[WS_BC + b * 64 + t];
    __syncthreads();
    int per = (N + NBLK_HIST - 1) / NBLK_HIST;
    int lo = b * per, hi = min(N, lo + per);
    for (int i = lo + t; i < hi; i += 256) {
        int pos = atomicAdd(&cur[spec[i]], 1);
        wsI[WS_ORDER + pos] = i;
    }
}

// ---- main: one 32-node same-species chunk per block, processed as two
//      16-node halves. Designed for ZERO register spills:
//      q[24] kept in regs (no nf re-read), weight frags JIT-loaded from
//      L2-hot global, MFMA results stored straight to out.
__global__ __launch_bounds__(THREADS) void k_main(
    const float* __restrict__ nf,
    const float* __restrict__ w0,
    const float* __restrict__ w1,
    const unsigned short* __restrict__ gkfrag,
    const float* __restrict__ gb,
    const unsigned short* __restrict__ lw0f,
    const unsigned short* __restrict__ lw1f,
    const int* __restrict__ wsI,
    float* __restrict__ out)
{
    int b = blockIdx.x;
    if (b >= wsI[WS_NCHUNKS]) return;
    int s     = wsI[WS_DESC + 3 * b];
    int start = wsI[WS_DESC + 3 * b + 1];
    int cnt   = wsI[WS_DESC + 3 * b + 2];

    __shared__ __align__(16) unsigned short s_ab[16 * 136];  // out0 / out0g bf16 (current half)
    __shared__ __align__(16) float s_u[3264];                // union: gate bf16 [16][280] / out1g bf16 [3][16][136]
    __shared__ int s_nid[CHUNK];

    int t = threadIdx.x;
    int lane = t & 63, w = t >> 6, lr = lane & 15, lg = lane >> 4;
    int nh = t >> 4, j = t & 15, f0 = 8 * j;

    if (t < CHUNK) s_nid[t] = (t < cnt) ? wsI[WS_ORDER + start + t] : -1;

    unsigned short* s_g  = (unsigned short*)s_u;   // gate bf16 [16][280]
    unsigned short* s_o1 = (unsigned short*)s_u;   // out1g bf16 [3][16][136]

    for (int h = 0; h < 2; ++h) {
        int n = h * 16 + nh;
        int nid = (n < cnt) ? wsI[WS_ORDER + start + n] : -1;
        const float* p = nf + (size_t)(nid >= 0 ? nid : 0) * 512;

        // ---- phase 1: polynomial paths (8 features/thread, q kept in regs) ----
        float x0[8], q[24], o0[8], c1[8], dot[8];
        *(float4*)&x0[0] = *(const float4*)&p[f0];
        *(float4*)&x0[4] = *(const float4*)&p[f0 + 4];
        #pragma unroll
        for (int v = 0; v < 6; ++v)
            *(float4*)&q[4 * v] = *(const float4*)&p[128 + 3 * f0 + 4 * v];
        if (nid < 0) {
            #pragma unroll
            for (int i = 0; i < 8; ++i) x0[i] = 0.f;
            #pragma unroll
            for (int i = 0; i < 24; ++i) q[i] = 0.f;
        }
        #pragma unroll
        for (int i = 0; i < 8; ++i)
            dot[i] = q[3 * i] * q[3 * i] + q[3 * i + 1] * q[3 * i + 1] + q[3 * i + 2] * q[3 * i + 2];

        {
            const float* W0 = w0 + s * 5 * F + f0;
            const float* W1 = w1 + s * 4 * F + f0;
            float wr[8];
            #define LOADW(base) { \
                *(float4*)&wr[0] = *(const float4*)&(base)[0]; \
                *(float4*)&wr[4] = *(const float4*)&(base)[4]; }
            LOADW(W0);
            #pragma unroll
            for (int i = 0; i < 8; ++i) o0[i] = x0[i] * wr[i];
            LOADW((W0 + F));
            #pragma unroll
            for (int i = 0; i < 8; ++i) o0[i] += x0[i] * x0[i] * wr[i];
            LOADW((W0 + 2 * F));
            #pragma unroll
            for (int i = 0; i < 8; ++i) o0[i] += dot[i] * wr[i];
            LOADW((W0 + 3 * F));
            #pragma unroll
            for (int i = 0; i < 8; ++i) o0[i] += x0[i] * x0[i] * x0[i] * wr[i];
            LOADW((W0 + 4 * F));
            #pragma unroll
            for (int i = 0; i < 8; ++i) o0[i] += x0[i] * dot[i] * wr[i];
            LOADW(W1);
            #pragma unroll
            for (int i = 0; i < 8; ++i) c1[i] = wr[i];
            LOADW((W1 + F));
            #pragma unroll
            for (int i = 0; i < 8; ++i) c1[i] += x0[i] * wr[i];
            LOADW((W1 + 2 * F));
            #pragma unroll
            for (int i = 0; i < 8; ++i) c1[i] += x0[i] * x0[i] * wr[i];
            LOADW((W1 + 3 * F));
            #pragma unroll
            for (int i = 0; i < 8; ++i) c1[i] += dot[i] * wr[i];
            #undef LOADW
        }
        {
            uint4 pk;
            pk.x = pack2(o0[0], o0[1]); pk.y = pack2(o0[2], o0[3]);
            pk.z = pack2(o0[4], o0[5]); pk.w = pack2(o0[6], o0[7]);
            *(uint4*)&s_ab[nh * 136 + f0] = pk;
        }
        __syncthreads();   // B1: out0 ready

        // ---- phase 2: gate = out0 @ gk + gb (JIT B-frags), bf16 to s_g ----
        {
            bf16x8 A[4];
            #pragma unroll
            for (int kk = 0; kk < 4; ++kk)
                A[kk] = *(const bf16x8*)&s_ab[lr * 136 + kk * 32 + lg * 8];
            #pragma unroll
            for (int oi = 0; oi < 4; ++oi) {
                float gbv = gb[s * NO + w * 64 + oi * 16 + lr];
                f32x4 acc; acc[0] = gbv; acc[1] = gbv; acc[2] = gbv; acc[3] = gbv;
                const unsigned short* gkb =
                    gkfrag + ((size_t)((s * 16 + 4 * w + oi) * 4)) * 512 + lane * 8;
                #pragma unroll
                for (int kk = 0; kk < 4; ++kk) {
                    bf16x8 Bf = *(const bf16x8*)(gkb + kk * 512);
                    acc = __builtin_amdgcn_mfma_f32_16x16x32_bf16(A[kk], Bf, acc, 0, 0, 0);
                }
                #pragma unroll
                for (int r = 0; r < 4; ++r)
                    s_g[(lg * 4 + r) * 280 + w * 64 + oi * 16 + lr] = f2bf(acc[r]);
            }
        }
        __syncthreads();   // B2: gate ready

        // ---- phase 3a: read gate (bf16) ----
        float g0[8], g1[8];
        {
            u16x8 va = *(const u16x8*)&s_g[nh * 280 + f0];
            u16x8 vb = *(const u16x8*)&s_g[nh * 280 + 128 + f0];
            #pragma unroll
            for (int i = 0; i < 8; ++i) { g0[i] = bf2f(va[i]); g1[i] = bf2f(vb[i]); }
        }
        __syncthreads();   // B3: s_g region reusable

        // ---- phase 3b: apply gate; out0g -> s_ab, out1g -> s_o1 ----
        {
            #pragma unroll
            for (int i = 0; i < 8; ++i) { o0[i] *= g0[i]; c1[i] *= g1[i]; }
            uint4 pk;
            pk.x = pack2(o0[0], o0[1]); pk.y = pack2(o0[2], o0[3]);
            pk.z = pack2(o0[4], o0[5]); pk.w = pack2(o0[6], o0[7]);
            *(uint4*)&s_ab[nh * 136 + f0] = pk;
            #pragma unroll
            for (int d = 0; d < 3; ++d) {
                uint4 p1;
                p1.x = pack2(c1[0] * q[0 + d],  c1[1] * q[3 + d]);
                p1.y = pack2(c1[2] * q[6 + d],  c1[3] * q[9 + d]);
                p1.z = pack2(c1[4] * q[12 + d], c1[5] * q[15 + d]);
                p1.w = pack2(c1[6] * q[18 + d], c1[7] * q[21 + d]);
                *(uint4*)&s_o1[(d * 16 + nh) * 136 + f0] = p1;
            }
        }
        __syncthreads();   // B4: out0g/out1g ready

        // ---- phase 4: y0/y1 MFMA (JIT lin frags), direct stores ----
        {
            int nids[4];
            #pragma unroll
            for (int r = 0; r < 4; ++r) nids[r] = s_nid[h * 16 + lg * 4 + r];

            bf16x8 A2[4];
            #pragma unroll
            for (int kk = 0; kk < 4; ++kk)
                A2[kk] = *(const bf16x8*)&s_ab[lr * 136 + kk * 32 + lg * 8];
            #pragma unroll
            for (int gi = 0; gi < 2; ++gi) {
                f32x4 acc = {0.f, 0.f, 0.f, 0.f};
                const unsigned short* l0b =
                    lw0f + (size_t)(((2 * w + gi) * 4)) * 512 + lane * 8;
                #pragma unroll
                for (int kk = 0; kk < 4; ++kk) {
                    bf16x8 Lf = *(const bf16x8*)(l0b + kk * 512);
                    acc = __builtin_amdgcn_mfma_f32_16x16x32_bf16(A2[kk], Lf, acc, 0, 0, 0);
                }
                #pragma unroll
                for (int r = 0; r < 4; ++r)
                    if (nids[r] >= 0)
                        out[(size_t)nids[r] * 512 + w * 32 + gi * 16 + lr] = acc[r];
            }
            #pragma unroll
            for (int d = 0; d < 3; ++d) {
                bf16x8 Ad[4];
                #pragma unroll
                for (int kk = 0; kk < 4; ++kk)
                    Ad[kk] = *(const bf16x8*)&s_o1[(d * 16 + lr) * 136 + kk * 32 + lg * 8];
                #pragma unroll
                for (int gi = 0; gi < 2; ++gi) {
                    f32x4 acc = {0.f, 0.f, 0.f, 0.f};
                    const unsigned short* l1b =
                        lw1f + (size_t)(((2 * w + gi) * 4)) * 512 + lane * 8;
                    #pragma unroll
                    for (int kk = 0; kk < 4; ++kk) {
                        bf16x8 Lf = *(const bf16x8*)(l1b + kk * 512);
                        acc = __builtin_amdgcn_mfma_f32_16x16x32_bf16(Ad[kk], Lf, acc, 0, 0, 0);
                    }
                    #pragma unroll
                    for (int r = 0; r < 4; ++r)
                        if (nids[r] >= 0)
                            out[(size_t)nids[r] * 512 + F + (w * 32 + gi * 16 + lr) * 3 + d] = acc[r];
                }
            }
        }
        if (h == 0) __syncthreads();   // B5: LDS reads done before next half overwrites
    }
}

extern "C" void kernel_launch(void* const* d_in, const int* in_sizes, int n_in,
                              void* d_out, int out_size, void* d_ws, size_t ws_size,
                              hipStream_t stream) {
    const float* nf  = (const float*)d_in[0];
    const int*  spec = (const int*)d_in[1];
    const float* w0  = (const float*)d_in[2];
    const float* w1  = (const float*)d_in[3];
    const float* gk  = (const float*)d_in[4];
    const float* gb  = (const float*)d_in[5];
    const float* lw0 = (const float*)d_in[6];
    const float* lw1 = (const float*)d_in[7];
    float* out = (float*)d_out;

    int N = in_sizes[0] / (4 * F);
    int S = in_sizes[5] / NO;
    int* wsI = (int*)d_ws;
    unsigned* gkfrag = (unsigned*)((char*)d_ws + WS_GKFRAG);
    unsigned* lw0f   = (unsigned*)((char*)d_ws + WS_LW0FRAG);
    unsigned* lw1f   = (unsigned*)((char*)d_ws + WS_LW1FRAG);

    k_prep<<<S + 2, 256, 0, stream>>>(gk, lw0, lw1, wsI, gkfrag, lw0f, lw1f, S);
    k_hist<<<NBLK_HIST, 256, 0, stream>>>(spec, N, wsI);
    k_plan<<<1, 64, 0, stream>>>(wsI, S);
    k_scatter<<<NBLK_HIST, 256, 0, stream>>>(spec, N, wsI);

    int maxc = (N + CHUNK - 1) / CHUNK + S;
    k_main<<<maxc, THREADS, 0, stream>>>(nf, w0, w1,
                                         (const unsigned short*)gkfrag, gb,
                                         (const unsigned short*)lw0f,
                                         (const unsigned short*)lw1f,
                                         wsI, out);
}